// Round 6
// baseline (15.617 us; speedup 1.0000x reference)
//
#include <hip/hip_runtime.h>
#include <math.h>

// Fused quanvolution + linear + log_softmax, closed-form circuit.
// Best-measured structure (R2): 1 wave per sample, no LDS, no barriers.
// This revision: __launch_bounds__(256,8) caps VGPRs at 64, and all x
// (HBM) loads are hoisted to the top of the wave as 8 independent float2
// loads so HBM latency is overlapped once, not per-patch.
//
// Closed form (verified vs the passing amplitude simulation, absmax 1.6e-2):
//   e0 = cos(t0)cos(t4)*cos(p0) - sin(t4)*sin(p0)*sin(p1+t1)
//   e1 = cos(t0)*cos(p0)*cos(p1+t1)
//   e2 = cos(p2)
//   e3 = cos(t3)*cos(p2)*cos(p3)
__global__ __launch_bounds__(256, 8) void quanv_fused_kernel(
    const float* __restrict__ x,      // [B,28,28]
    const float* __restrict__ theta,  // [6]
    const float* __restrict__ W,      // [10,784]
    const float* __restrict__ bias,   // [10]
    float* __restrict__ out)          // [B,10] log-probs
{
    const int wave = threadIdx.x >> 6;
    const int lane = threadIdx.x & 63;
    const int b    = blockIdx.x * 4 + wave;

    const float* __restrict__ xb = x + (size_t)b * 784;

    // ---- hoisted x loads: issue every HBM access up front ----
    float2 t01[3], t23[3], u01, u23;
#pragma unroll
    for (int i = 0; i < 3; ++i) {
        const int p = lane + 64 * i;
        const int r = p / 14, c = p - r * 14;
        const float* px = xb + r * 56 + c * 2;
        t01[i] = *reinterpret_cast<const float2*>(px);
        t23[i] = *reinterpret_cast<const float2*>(px + 28);
    }
    const bool tail = (lane < 4);
    if (tail) {
        const float* px = xb + 13 * 56 + (10 + lane) * 2;  // p = 192+lane
        u01 = *reinterpret_cast<const float2*>(px);
        u23 = *reinterpret_cast<const float2*>(px + 28);
    }

    // theta-derived constants (loop-invariant broadcast)
    const float t1 = theta[1];
    const float K1 = __cosf(theta[0]) * __cosf(theta[4]);  // cos t0 cos t4
    const float K2 = __sinf(theta[4]);                     // sin t4
    const float K3 = __cosf(theta[0]);                     // cos t0
    const float K4 = __cosf(theta[3]);                     // cos t3

    float acc[10];
#pragma unroll
    for (int k = 0; k < 10; ++k) acc[k] = 0.f;

    auto fma_patch = [&](int p, float2 a01, float2 a23) {
        float sp0, cp0, sph, cph;
        __sincosf(a01.x, &sp0, &cp0);        // sin p0, cos p0
        __sincosf(a01.y + t1, &sph, &cph);   // sin/cos(p1 + t1)
        const float cp2 = __cosf(a23.x);
        const float cp3 = __cosf(a23.y);

        const float e0 = K1 * cp0 - K2 * sp0 * sph;
        const float e1 = K3 * cp0 * cph;
        const float e2 = cp2;
        const float e3 = K4 * cp2 * cp3;

#pragma unroll
        for (int k = 0; k < 10; ++k) {
            const float4 w4 = *reinterpret_cast<const float4*>(&W[k * 784 + 4 * p]);
            acc[k] += e0 * w4.x + e1 * w4.y + e2 * w4.z + e3 * w4.w;
        }
    };

#pragma unroll
    for (int i = 0; i < 3; ++i) fma_patch(lane + 64 * i, t01[i], t23[i]);
    if (tail) fma_patch(192 + lane, u01, u23);   // 196 = 3*64 + 4

    // in-wave butterfly: afterwards every lane holds all 10 full sums
#pragma unroll
    for (int m = 1; m < 64; m <<= 1) {
#pragma unroll
        for (int k = 0; k < 10; ++k) acc[k] += __shfl_xor(acc[k], m, 64);
    }

    // lane-parallel log_softmax (lanes 0..9), coalesced 40B store
    float v = acc[0];
#pragma unroll
    for (int k = 1; k < 10; ++k) v = (lane == k) ? acc[k] : v;
    v += bias[lane < 10 ? lane : 0];

    float m = (lane < 10) ? v : -1e30f;
#pragma unroll
    for (int off = 1; off < 16; off <<= 1) m = fmaxf(m, __shfl_xor(m, off, 16));
    float s = (lane < 10) ? __expf(v - m) : 0.f;
#pragma unroll
    for (int off = 1; off < 16; off <<= 1) s += __shfl_xor(s, off, 16);
    const float lse = m + __logf(s);

    if (lane < 10) out[(size_t)b * 10 + lane] = v - lse;
}

extern "C" void kernel_launch(void* const* d_in, const int* in_sizes, int n_in,
                              void* d_out, int out_size, void* d_ws, size_t ws_size,
                              hipStream_t stream) {
    const float* x     = (const float*)d_in[0];  // [B,28,28]
    const float* theta = (const float*)d_in[1];  // [6]
    const float* W     = (const float*)d_in[2];  // [10,784]
    const float* bias  = (const float*)d_in[3];  // [10]
    float* out = (float*)d_out;                  // [B,10]

    const int B = in_sizes[0] / 784;             // 4096 (multiple of 4)
    quanv_fused_kernel<<<dim3(B / 4), dim3(256), 0, stream>>>(x, theta, W, bias, out);
}

// Round 7
// 12.366 us; speedup vs baseline: 1.2629x; 1.2629x over previous
//
#include <hip/hip_runtime.h>
#include <math.h>

// Fused quanvolution + linear + log_softmax, closed-form circuit.
// Structure = R2 winner (1 wave/sample, no barriers in the matvec, no
// launch_bounds) + W staged in LDS once per block (31.4 KB shared by the
// block's 4 samples -> 4x less L1/L2 W traffic; ds_read_b128 at 16B lane
// stride is bank-conflict-free).
//
// Closed form (verified vs the passing amplitude simulation, absmax 1.6e-2):
//   e0 = cos(t0)cos(t4)*cos(p0) - sin(t4)*sin(p0)*sin(p1+t1)
//   e1 = cos(t0)*cos(p0)*cos(p1+t1)
//   e2 = cos(p2)
//   e3 = cos(t3)*cos(p2)*cos(p3)
__global__ __launch_bounds__(256) void quanv_fused_kernel(
    const float* __restrict__ x,      // [B,28,28]
    const float* __restrict__ theta,  // [6]
    const float* __restrict__ W,      // [10,784]
    const float* __restrict__ bias,   // [10]
    float* __restrict__ out)          // [B,10] log-probs
{
    __shared__ float Wlds[7840];      // [10][784], 31.36 KB

    const int tid  = threadIdx.x;
    const int wave = tid >> 6;
    const int lane = tid & 63;
    const int b    = blockIdx.x * 4 + wave;

    // ---- cooperative W stage: 1960 float4s over 256 threads ----
    {
        const float4* __restrict__ Wg = reinterpret_cast<const float4*>(W);
        float4* Wl = reinterpret_cast<float4*>(Wlds);
        for (int i = tid; i < 1960; i += 256) Wl[i] = Wg[i];
    }
    __syncthreads();

    // theta-derived constants (loop-invariant broadcast)
    const float t1 = theta[1];
    const float K1 = __cosf(theta[0]) * __cosf(theta[4]);  // cos t0 cos t4
    const float K2 = __sinf(theta[4]);                     // sin t4
    const float K3 = __cosf(theta[0]);                     // cos t0
    const float K4 = __cosf(theta[3]);                     // cos t3

    const float* __restrict__ xb = x + (size_t)b * 784;

    float acc[10];
#pragma unroll
    for (int k = 0; k < 10; ++k) acc[k] = 0.f;

    auto do_patch = [&](int p) {
        const int r = p / 14, c = p - r * 14;
        const float* px = xb + r * 56 + c * 2;
        const float2 t01 = *reinterpret_cast<const float2*>(px);
        const float2 t23 = *reinterpret_cast<const float2*>(px + 28);

        float sp0, cp0, sph, cph;
        __sincosf(t01.x, &sp0, &cp0);        // sin p0, cos p0
        __sincosf(t01.y + t1, &sph, &cph);   // sin/cos(p1 + t1)
        const float cp2 = __cosf(t23.x);
        const float cp3 = __cosf(t23.y);

        const float e0 = K1 * cp0 - K2 * sp0 * sph;
        const float e1 = K3 * cp0 * cph;
        const float e2 = cp2;
        const float e3 = K4 * cp2 * cp3;

#pragma unroll
        for (int k = 0; k < 10; ++k) {
            const float4 w4 = *reinterpret_cast<const float4*>(&Wlds[k * 784 + 4 * p]);
            acc[k] += e0 * w4.x + e1 * w4.y + e2 * w4.z + e3 * w4.w;
        }
    };

#pragma unroll
    for (int i = 0; i < 3; ++i) do_patch(lane + 64 * i);
    if (lane < 4) do_patch(192 + lane);      // 196 = 3*64 + 4

    // in-wave butterfly: afterwards every lane holds all 10 full sums
#pragma unroll
    for (int m = 1; m < 64; m <<= 1) {
#pragma unroll
        for (int k = 0; k < 10; ++k) acc[k] += __shfl_xor(acc[k], m, 64);
    }

    // lane-parallel log_softmax (lanes 0..9), coalesced 40B store
    float v = acc[0];
#pragma unroll
    for (int k = 1; k < 10; ++k) v = (lane == k) ? acc[k] : v;
    v += bias[lane < 10 ? lane : 0];

    float m = (lane < 10) ? v : -1e30f;
#pragma unroll
    for (int off = 1; off < 16; off <<= 1) m = fmaxf(m, __shfl_xor(m, off, 16));
    float s = (lane < 10) ? __expf(v - m) : 0.f;
#pragma unroll
    for (int off = 1; off < 16; off <<= 1) s += __shfl_xor(s, off, 16);
    const float lse = m + __logf(s);

    if (lane < 10) out[(size_t)b * 10 + lane] = v - lse;
}

extern "C" void kernel_launch(void* const* d_in, const int* in_sizes, int n_in,
                              void* d_out, int out_size, void* d_ws, size_t ws_size,
                              hipStream_t stream) {
    const float* x     = (const float*)d_in[0];  // [B,28,28]
    const float* theta = (const float*)d_in[1];  // [6]
    const float* W     = (const float*)d_in[2];  // [10,784]
    const float* bias  = (const float*)d_in[3];  // [10]
    float* out = (float*)d_out;                  // [B,10]

    const int B = in_sizes[0] / 784;             // 4096 (multiple of 4)
    quanv_fused_kernel<<<dim3(B / 4), dim3(256), 0, stream>>>(x, theta, W, bias, out);
}

// Round 9
// 11.594 us; speedup vs baseline: 1.3470x; 1.0666x over previous
//
#include <hip/hip_runtime.h>
#include <math.h>

// Fused quanvolution + linear + log_softmax, closed-form circuit.
// R7 structure (1 wave/sample, W staged in LDS, no launch_bounds cap)
// + W stored in LDS as f16 and consumed via v_dot2_f32_f16:
//   - one ds_read_b128 now carries 2 classes x 4 coefs -> 5 reads/patch
//     (was 10), halving the LDS-pipe demand that R7's counters showed to be
//     the kernel-side bottleneck (~496 b128/CU ~ 2.5us).
//   - 20 fdot2 replace 40 f32 FMA per patch.
// LDS layout Wlds[p*5+kk] = 8 f16 {W[2kk][4p..4p+3], W[2kk+1][4p..4p+3]};
// 80B lane stride is bank-conflict-optimal for b128.
//
// Closed form (verified vs the passing amplitude simulation, absmax 1.6e-2):
//   e0 = cos(t0)cos(t4)*cos(p0) - sin(t4)*sin(p0)*sin(p1+t1)
//   e1 = cos(t0)*cos(p0)*cos(p1+t1)
//   e2 = cos(p2)
//   e3 = cos(t3)*cos(p2)*cos(p3)

typedef __attribute__((ext_vector_type(2))) _Float16 half2v;

static __device__ __forceinline__ float fdot2f(half2v a, half2v b, float c) {
#if __has_builtin(__builtin_amdgcn_fdot2)
    return __builtin_amdgcn_fdot2(a, b, c, false);   // v_dot2_f32_f16, f32 accum
#else
    return c + (float)a.x * (float)b.x + (float)a.y * (float)b.y;
#endif
}

static __device__ __forceinline__ unsigned int pkh2(float a, float b) {
#if __has_builtin(__builtin_amdgcn_cvt_pkrtz)
    return __builtin_bit_cast(unsigned int, __builtin_amdgcn_cvt_pkrtz(a, b));
#else
    half2v h = { (_Float16)a, (_Float16)b };
    return __builtin_bit_cast(unsigned int, h);
#endif
}

static __device__ __forceinline__ half2v ash2(unsigned int u) {
    return __builtin_bit_cast(half2v, u);
}

__global__ __launch_bounds__(256) void quanv_fused_kernel(
    const float* __restrict__ x,      // [B,28,28]
    const float* __restrict__ theta,  // [6]
    const float* __restrict__ W,      // [10,784]
    const float* __restrict__ bias,   // [10]
    float* __restrict__ out)          // [B,10] log-probs
{
    __shared__ uint4 Wlds[980];       // [196][5] : 15.7 KB of f16 weights

    const int tid  = threadIdx.x;
    const int wave = tid >> 6;
    const int lane = tid & 63;
    const int b    = blockIdx.x * 4 + wave;

    // ---- cooperative W stage: f32 -> f16, 980 groups of (patch, class-pair) ----
    {
        const float4* __restrict__ Wg = reinterpret_cast<const float4*>(W);
        for (int g = tid; g < 980; g += 256) {
            const int p  = g % 196;            // consecutive tid -> consecutive p: coalesced
            const int kk = g / 196;
            const float4 fa = Wg[(2 * kk)     * 196 + p];
            const float4 fb = Wg[(2 * kk + 1) * 196 + p];
            Wlds[p * 5 + kk] = make_uint4(pkh2(fa.x, fa.y), pkh2(fa.z, fa.w),
                                          pkh2(fb.x, fb.y), pkh2(fb.z, fb.w));
        }
    }
    __syncthreads();

    // theta-derived constants (loop-invariant broadcast)
    const float t1 = theta[1];
    const float K1 = __cosf(theta[0]) * __cosf(theta[4]);  // cos t0 cos t4
    const float K2 = __sinf(theta[4]);                     // sin t4
    const float K3 = __cosf(theta[0]);                     // cos t0
    const float K4 = __cosf(theta[3]);                     // cos t3

    const float* __restrict__ xb = x + (size_t)b * 784;

    float acc[10];
#pragma unroll
    for (int k = 0; k < 10; ++k) acc[k] = 0.f;

    auto do_patch = [&](int p) {
        const int r = p / 14, c = p - r * 14;
        const float* px = xb + r * 56 + c * 2;
        const float2 t01 = *reinterpret_cast<const float2*>(px);
        const float2 t23 = *reinterpret_cast<const float2*>(px + 28);

        float sp0, cp0, sph, cph;
        __sincosf(t01.x, &sp0, &cp0);        // sin p0, cos p0
        __sincosf(t01.y + t1, &sph, &cph);   // sin/cos(p1 + t1)
        const float cp2 = __cosf(t23.x);
        const float cp3 = __cosf(t23.y);

        const float e0 = K1 * cp0 - K2 * sp0 * sph;
        const float e1 = K3 * cp0 * cph;
        const float e2 = cp2;
        const float e3 = K4 * cp2 * cp3;

        const half2v e01 = ash2(pkh2(e0, e1));
        const half2v e23 = ash2(pkh2(e2, e3));

        const uint4* __restrict__ row = &Wlds[p * 5];
#pragma unroll
        for (int kk = 0; kk < 5; ++kk) {
            const uint4 w = row[kk];         // 1 ds_read_b128 = 2 classes x 4 coefs
            acc[2 * kk]     = fdot2f(ash2(w.x), e01, acc[2 * kk]);
            acc[2 * kk]     = fdot2f(ash2(w.y), e23, acc[2 * kk]);
            acc[2 * kk + 1] = fdot2f(ash2(w.z), e01, acc[2 * kk + 1]);
            acc[2 * kk + 1] = fdot2f(ash2(w.w), e23, acc[2 * kk + 1]);
        }
    };

#pragma unroll
    for (int i = 0; i < 3; ++i) do_patch(lane + 64 * i);
    if (lane < 4) do_patch(192 + lane);      // 196 = 3*64 + 4

    // in-wave butterfly: afterwards every lane holds all 10 full sums
#pragma unroll
    for (int m = 1; m < 64; m <<= 1) {
#pragma unroll
        for (int k = 0; k < 10; ++k) acc[k] += __shfl_xor(acc[k], m, 64);
    }

    // lane-parallel log_softmax (lanes 0..9), coalesced 40B store
    float v = acc[0];
#pragma unroll
    for (int k = 1; k < 10; ++k) v = (lane == k) ? acc[k] : v;
    v += bias[lane < 10 ? lane : 0];

    float m = (lane < 10) ? v : -1e30f;
#pragma unroll
    for (int off = 1; off < 16; off <<= 1) m = fmaxf(m, __shfl_xor(m, off, 16));
    float s = (lane < 10) ? __expf(v - m) : 0.f;
#pragma unroll
    for (int off = 1; off < 16; off <<= 1) s += __shfl_xor(s, off, 16);
    const float lse = m + __logf(s);

    if (lane < 10) out[(size_t)b * 10 + lane] = v - lse;
}

extern "C" void kernel_launch(void* const* d_in, const int* in_sizes, int n_in,
                              void* d_out, int out_size, void* d_ws, size_t ws_size,
                              hipStream_t stream) {
    const float* x     = (const float*)d_in[0];  // [B,28,28]
    const float* theta = (const float*)d_in[1];  // [6]
    const float* W     = (const float*)d_in[2];  // [10,784]
    const float* bias  = (const float*)d_in[3];  // [10]
    float* out = (float*)d_out;                  // [B,10]

    const int B = in_sizes[0] / 784;             // 4096 (multiple of 4)
    quanv_fused_kernel<<<dim3(B / 4), dim3(256), 0, stream>>>(x, theta, W, bias, out);
}

// Round 10
// 11.251 us; speedup vs baseline: 1.3880x; 1.0305x over previous
//
#include <hip/hip_runtime.h>
#include <math.h>

// Fused quanvolution + linear + log_softmax, closed-form circuit.
// R8 structure (W f16 in LDS, v_dot2_f32_f16, 5 ds_read_b128/patch)
// + 2 samples per wave: each W row read from LDS feeds BOTH samples'
// fdot2s -> chip-wide LDS-pipe demand halves (R8's dominant kernel term),
// total VALU/trig/x traffic unchanged (half the waves, 2x work each).
//
// Closed form (verified vs the passing amplitude simulation, absmax 1.6e-2):
//   e0 = cos(t0)cos(t4)*cos(p0) - sin(t4)*sin(p0)*sin(p1+t1)
//   e1 = cos(t0)*cos(p0)*cos(p1+t1)
//   e2 = cos(p2)
//   e3 = cos(t3)*cos(p2)*cos(p3)

typedef __attribute__((ext_vector_type(2))) _Float16 half2v;

static __device__ __forceinline__ float fdot2f(half2v a, half2v b, float c) {
#if __has_builtin(__builtin_amdgcn_fdot2)
    return __builtin_amdgcn_fdot2(a, b, c, false);   // v_dot2_f32_f16, f32 accum
#else
    return c + (float)a.x * (float)b.x + (float)a.y * (float)b.y;
#endif
}

static __device__ __forceinline__ unsigned int pkh2(float a, float b) {
#if __has_builtin(__builtin_amdgcn_cvt_pkrtz)
    return __builtin_bit_cast(unsigned int, __builtin_amdgcn_cvt_pkrtz(a, b));
#else
    half2v h = { (_Float16)a, (_Float16)b };
    return __builtin_bit_cast(unsigned int, h);
#endif
}

static __device__ __forceinline__ half2v ash2(unsigned int u) {
    return __builtin_bit_cast(half2v, u);
}

__global__ __launch_bounds__(256) void quanv_fused_kernel(
    const float* __restrict__ x,      // [B,28,28]
    const float* __restrict__ theta,  // [6]
    const float* __restrict__ W,      // [10,784]
    const float* __restrict__ bias,   // [10]
    float* __restrict__ out)          // [B,10] log-probs
{
    __shared__ uint4 Wlds[980];       // [196][5] : 15.7 KB of f16 weights

    const int tid  = threadIdx.x;
    const int wv   = tid >> 6;
    const int lane = tid & 63;
    const int b0   = blockIdx.x * 8 + wv * 2;   // wave handles samples b0, b0+1

    // ---- cooperative W stage: f32 -> f16, 980 (patch, class-pair) groups ----
    {
        const float4* __restrict__ Wg = reinterpret_cast<const float4*>(W);
        for (int g = tid; g < 980; g += 256) {
            const int p  = g % 196;            // consecutive tid -> consecutive p
            const int kk = g / 196;
            const float4 fa = Wg[(2 * kk)     * 196 + p];
            const float4 fb = Wg[(2 * kk + 1) * 196 + p];
            Wlds[p * 5 + kk] = make_uint4(pkh2(fa.x, fa.y), pkh2(fa.z, fa.w),
                                          pkh2(fb.x, fb.y), pkh2(fb.z, fb.w));
        }
    }
    __syncthreads();

    // theta-derived constants (loop-invariant broadcast)
    const float t1 = theta[1];
    const float K1 = __cosf(theta[0]) * __cosf(theta[4]);  // cos t0 cos t4
    const float K2 = __sinf(theta[4]);                     // sin t4
    const float K3 = __cosf(theta[0]);                     // cos t0
    const float K4 = __cosf(theta[3]);                     // cos t3

    const float* __restrict__ xa = x + (size_t)b0 * 784;
    const float* __restrict__ xb = xa + 784;

    float acc0[10], acc1[10];
#pragma unroll
    for (int k = 0; k < 10; ++k) { acc0[k] = 0.f; acc1[k] = 0.f; }

    // e-vector (packed f16 pairs) for one sample's patch
    auto evec = [&](const float* __restrict__ xs, const float* px_off,
                    unsigned int& e01, unsigned int& e23, int off) {
        const float2 t01 = *reinterpret_cast<const float2*>(px_off + off);
        const float2 t23 = *reinterpret_cast<const float2*>(px_off + off + 28);
        float sp0, cp0, sph, cph;
        __sincosf(t01.x, &sp0, &cp0);
        __sincosf(t01.y + t1, &sph, &cph);
        const float cp2 = __cosf(t23.x);
        const float cp3 = __cosf(t23.y);
        const float e0 = K1 * cp0 - K2 * sp0 * sph;
        const float e1 = K3 * cp0 * cph;
        e01 = pkh2(e0, e1);
        e23 = pkh2(cp2, K4 * cp2 * cp3);
        (void)xs;
    };

    auto do_patch = [&](int p) {
        const int r = p / 14, c = p - r * 14;
        const int off = r * 56 + c * 2;
        unsigned int a01, a23, b01, b23;
        evec(xa, xa, a01, a23, off);
        evec(xb, xb, b01, b23, off);
        const half2v ea01 = ash2(a01), ea23 = ash2(a23);
        const half2v eb01 = ash2(b01), eb23 = ash2(b23);

        const uint4* __restrict__ row = &Wlds[p * 5];
#pragma unroll
        for (int kk = 0; kk < 5; ++kk) {
            const uint4 w = row[kk];         // 1 ds_read_b128 feeds both samples
            acc0[2 * kk]     = fdot2f(ash2(w.x), ea01, acc0[2 * kk]);
            acc0[2 * kk]     = fdot2f(ash2(w.y), ea23, acc0[2 * kk]);
            acc0[2 * kk + 1] = fdot2f(ash2(w.z), ea01, acc0[2 * kk + 1]);
            acc0[2 * kk + 1] = fdot2f(ash2(w.w), ea23, acc0[2 * kk + 1]);
            acc1[2 * kk]     = fdot2f(ash2(w.x), eb01, acc1[2 * kk]);
            acc1[2 * kk]     = fdot2f(ash2(w.y), eb23, acc1[2 * kk]);
            acc1[2 * kk + 1] = fdot2f(ash2(w.z), eb01, acc1[2 * kk + 1]);
            acc1[2 * kk + 1] = fdot2f(ash2(w.w), eb23, acc1[2 * kk + 1]);
        }
    };

#pragma unroll
    for (int i = 0; i < 3; ++i) do_patch(lane + 64 * i);
    if (lane < 4) do_patch(192 + lane);      // 196 = 3*64 + 4

    // in-wave butterfly for both accumulator sets
#pragma unroll
    for (int m = 1; m < 64; m <<= 1) {
#pragma unroll
        for (int k = 0; k < 10; ++k) {
            acc0[k] += __shfl_xor(acc0[k], m, 64);
            acc1[k] += __shfl_xor(acc1[k], m, 64);
        }
    }

    // epilogue: 16-lane group 0 -> sample b0, group 1 -> sample b0+1
    float v = acc0[0];
#pragma unroll
    for (int k = 1; k < 10; ++k) v = (lane == k) ? acc0[k] : v;
#pragma unroll
    for (int k = 0; k < 10; ++k) v = (lane == 16 + k) ? acc1[k] : v;

    const int cls = lane & 15;
    const bool act = (cls < 10) && (lane < 32);
    v += bias[cls < 10 ? cls : 0];

    float m = act ? v : -1e30f;
#pragma unroll
    for (int off = 1; off < 16; off <<= 1) m = fmaxf(m, __shfl_xor(m, off, 16));
    float s = act ? __expf(v - m) : 0.f;
#pragma unroll
    for (int off = 1; off < 16; off <<= 1) s += __shfl_xor(s, off, 16);
    const float lse = m + __logf(s);

    if (act) out[(size_t)(b0 + (lane >> 4)) * 10 + cls] = v - lse;
}

extern "C" void kernel_launch(void* const* d_in, const int* in_sizes, int n_in,
                              void* d_out, int out_size, void* d_ws, size_t ws_size,
                              hipStream_t stream) {
    const float* x     = (const float*)d_in[0];  // [B,28,28]
    const float* theta = (const float*)d_in[1];  // [6]
    const float* W     = (const float*)d_in[2];  // [10,784]
    const float* bias  = (const float*)d_in[3];  // [10]
    float* out = (float*)d_out;                  // [B,10]

    const int B = in_sizes[0] / 784;             // 4096 (multiple of 8)
    quanv_fused_kernel<<<dim3(B / 8), dim3(256), 0, stream>>>(x, theta, W, bias, out);
}